// Round 1
// baseline (91.774 us; speedup 1.0000x reference)
//
#include <hip/hip_runtime.h>

// HONU order-3: out[b] = sum_{i0<=i1<=i2} w[m(i0,i1,i2)] * xb[b,i0]*xb[b,i1]*xb[b,i2]
// xb = [1, x] (129 features). comb_idx is lex-ordered combinations_with_replacement,
// so m is computed analytically; the comb_idx input is ignored entirely.

#define NF     129      // features incl. bias
#define NX     128      // raw features
#define NPAIR  8385     // #(i0<=i1) pairs = 129*130/2
#define NCOMB  366145   // #(i0<=i1<=i2) triples = C(131,3)
#define ROWS   64       // batch rows per tile (= wave width)
#define NBLKX  256      // combo-parallel blocks per batch tile
#define WAVES  4
#define WSLOTS (NBLKX*WAVES)   // 1024 wave slots per batch tile

__launch_bounds__(256, 4)
__global__ void honu_kernel(const float* __restrict__ x,
                            const float* __restrict__ weight,
                            float* __restrict__ out) {
    __shared__ float xb[ROWS * NF];   // [row][feat], feat 0 = bias (stride 129: bank-conflict-free)
    __shared__ float red[256];

    const int tid  = threadIdx.x;
    const int lane = tid & 63;
    const int w    = tid >> 6;
    const int row0 = blockIdx.y * ROWS;

    // ---- stage x tile (64 rows x 128 feats) into LDS, float4 global loads ----
    {
        const float4* xv = (const float4*)(x + (size_t)row0 * NX);
        #pragma unroll
        for (int it = 0; it < 8; ++it) {
            int idx = tid + it * 256;        // 0..2047 float4s
            int r   = idx >> 5;              // 32 float4 per row
            int fc  = (idx & 31) << 2;
            float4 v = xv[idx];
            float* dst = &xb[r * NF + 1 + fc];
            dst[0] = v.x; dst[1] = v.y; dst[2] = v.z; dst[3] = v.w;
        }
        if (tid < ROWS) xb[tid * NF] = 1.0f;   // bias column
    }
    __syncthreads();

    const float* xrow = &xb[lane * NF];
    float acc = 0.0f;

    const int ws = blockIdx.x * WAVES + w;     // wave slot in [0, WSLOTS)
    for (int p = ws; p < NPAIR; p += WSLOTS) {
        // decode pair p -> (i0, i1); off(i) = i*(259-i)/2 = #pairs with first < i
        int i0 = (int)((259.0f - sqrtf((float)(67081 - 8 * p))) * 0.5f);
        i0 = i0 < 0 ? 0 : (i0 > 128 ? 128 : i0);
        while (i0 < 128 && ((i0 + 1) * (258 - i0)) / 2 <= p) ++i0;
        while (i0 > 0   && (i0 * (259 - i0)) / 2      >  p) --i0;
        const int i1 = i0 + (p - (i0 * (259 - i0)) / 2);

        // flat combo index of (i0, i1, i1):
        // m = T(129) - T(129-i0) + C2(129-i0) - C2(129-i1),  T(n)=n(n+1)(n+2)/6
        const int n0 = NF - i0, n1 = NF - i1;
        int m = NCOMB - (n0 * (n0 + 1) * (n0 + 2)) / 6
                      + ((n0 * (n0 + 1)) >> 1)
                      - ((n1 * (n1 + 1)) >> 1);

        const float p01 = xrow[i0] * xrow[i1];
        #pragma unroll 4
        for (int i2 = i1; i2 < NF; ++i2, ++m) {
            acc = fmaf(weight[m], p01 * xrow[i2], acc);
        }
    }

    // ---- reduce 4 waves -> 64 rows, one atomic per row per block ----
    red[tid] = acc;
    __syncthreads();
    if (tid < ROWS) {
        float s = red[tid] + red[tid + 64] + red[tid + 128] + red[tid + 192];
        atomicAdd(&out[row0 + tid], s);
    }
}

extern "C" void kernel_launch(void* const* d_in, const int* in_sizes, int n_in,
                              void* d_out, int out_size, void* d_ws, size_t ws_size,
                              hipStream_t stream) {
    const float* x      = (const float*)d_in[0];
    const float* weight = (const float*)d_in[1];
    // d_in[2] (comb_idx) intentionally unused: indices are lex-order, computed analytically.
    float* out = (float*)d_out;

    hipMemsetAsync(out, 0, (size_t)out_size * sizeof(float), stream);
    dim3 grid(NBLKX, 256 / ROWS);
    honu_kernel<<<grid, 256, 0, stream>>>(x, weight, out);
}